// Round 9
// baseline (174.771 us; speedup 1.0000x reference)
//
#include <hip/hip_runtime.h>
#include <math.h>

#define N_NODES 50000
#define N_EDGES 1600000
#define IN_DIM 256
#define HID_DIM 128
#define OUT_DIM 40
#define N2 48          // OUT_DIM padded to MFMA multiple
#define H2S 40         // h2b row stride (elems): 50048*40*2B = 4.0 MB -> fits per-XCD L2
#define ZROW N_NODES   // dedicated all-zero row index for CSR padding
#define NROWS 50048    // row allocation (covers pad + tile overrun)

#define NB 196         // dst buckets of 256 nodes
#define BCAP 10240     // part[] slots per bucket
#define SEGSTRIDE 12288
#define PCHUNK 8192
#define NPB ((N_EDGES + PCHUNK - 1) / PCHUNK)  // 196

typedef __attribute__((ext_vector_type(8))) short bf16x8;
typedef __attribute__((ext_vector_type(4))) float f32x4;
typedef __attribute__((ext_vector_type(2))) float f32x2;

// ---------------- bf16 helpers (RNE) ----------------
__device__ __forceinline__ unsigned int f2bf(float f) {
    unsigned int u = __float_as_uint(f);
    unsigned int r = u + 0x7FFFu + ((u >> 16) & 1u);
    return r >> 16;
}
__device__ __forceinline__ float bf2f(unsigned short s) {
    return __uint_as_float(((unsigned int)s) << 16);
}

// ---------------- init: gcursor bases + zero rows ----------------
__global__ void k_init(int* __restrict__ gcursor,
                       unsigned short* __restrict__ h1b,
                       unsigned short* __restrict__ h2b) {
    int i = threadIdx.x;
    if (i < NB) gcursor[i] = i * BCAP;
    if (i < HID_DIM) h1b[(size_t)ZROW * HID_DIM + i] = 0;
    if (i < H2S) h2b[(size_t)ZROW * H2S + i] = 0;
}

// ---------------- partition edges into 196 dst-buckets (4B packed entries) ----------------
// entry: bits[15:0] = src (N<65536), bits[23:16] = dst&255
__global__ __launch_bounds__(256) void k_part(const int* __restrict__ src,
                                              const int* __restrict__ dst,
                                              int* __restrict__ gcursor,
                                              unsigned int* __restrict__ part) {
    __shared__ int hist[NB];
    __shared__ int lcur[NB];
    const int tid = threadIdx.x;
    const int base = blockIdx.x * PCHUNK;
    const int n = min(PCHUNK, N_EDGES - base);

    for (int i = tid; i < NB; i += 256) hist[i] = 0;
    __syncthreads();
    for (int i = tid; i < n; i += 256)
        atomicAdd(&hist[dst[base + i] >> 8], 1);
    __syncthreads();
    for (int i = tid; i < NB; i += 256)
        lcur[i] = atomicAdd(&gcursor[i], hist[i]);
    __syncthreads();
    for (int i = tid; i < n; i += 256) {
        int d = dst[base + i];
        int g = d >> 8;
        int pos = atomicAdd(&lcur[g], 1);
        part[pos] = ((unsigned int)(d & 255) << 16) | (unsigned int)src[base + i];
    }
}

// ---------------- per-bucket counting sort: row_beg/row_end/dinv + padded csr ----------------
__global__ __launch_bounds__(256) void k_bucket(const unsigned int* __restrict__ part,
                                                const int* __restrict__ gcursor,
                                                int* __restrict__ row_beg,
                                                int* __restrict__ row_end,
                                                float* __restrict__ dinv,
                                                int* __restrict__ csr) {
    __shared__ int hist[256];
    __shared__ int sh[256];
    __shared__ int cur[256];
    const int g = blockIdx.x;
    const int tid = threadIdx.x;
    const int ebase = g * BCAP;
    const int ecnt = gcursor[g] - ebase;
    const int cbase = g * SEGSTRIDE;

    hist[tid] = 0;
    __syncthreads();
    for (int i = tid; i < ecnt; i += 256)
        atomicAdd(&hist[(part[ebase + i] >> 16) & 255], 1);
    __syncthreads();

    int own = hist[tid];
    int pcnt = (own + 7) & ~7;  // pad each node's segment to x8
    sh[tid] = pcnt;
    __syncthreads();
    for (int off = 1; off < 256; off <<= 1) {
        int t = (tid >= off) ? sh[tid - off] : 0;
        __syncthreads();
        sh[tid] += t;
        __syncthreads();
    }
    int pexcl = sh[tid] - pcnt;

    int node = (g << 8) + tid;
    if (node < N_NODES) {
        row_beg[node] = cbase + pexcl;
        row_end[node] = cbase + pexcl + pcnt;
        dinv[node] = rsqrtf((float)own + 1.0f);
    }
    cur[tid] = cbase + pexcl;
    for (int p = own; p < pcnt; ++p) csr[cbase + pexcl + p] = ZROW;
    __syncthreads();

    for (int i = tid; i < ecnt; i += 256) {
        unsigned int p = part[ebase + i];
        int pos = atomicAdd(&cur[(p >> 16) & 255], 1);
        csr[pos] = (int)(p & 0xFFFFu);
    }
}

// ---------------- W1^T bf16 [128][256] ----------------
__global__ __launch_bounds__(256) void k_w1t(const float* __restrict__ W1,
                                             unsigned short* __restrict__ w1t) {
    int c = blockIdx.x;
    int k = threadIdx.x;
    w1t[c * IN_DIM + k] = (unsigned short)f2bf(W1[k * HID_DIM + c]);
}

// ---------------- W2^T bf16 [48][128] (cols 40..47 zero) ----------------
__global__ __launch_bounds__(128) void k_w2t(const float* __restrict__ W2,
                                             unsigned short* __restrict__ w2t) {
    int c = blockIdx.x;   // 0..47
    int k = threadIdx.x;  // 0..127
    w2t[c * HID_DIM + k] = (c < OUT_DIM) ? (unsigned short)f2bf(W2[k * OUT_DIM + c]) : 0;
}

// ---------------- GEMM1 (MFMA): h1b[N][128](bf16) = dinv * (x @ W1) ----------------
// 128x128 tile per block, 4 waves x (32 rows x 128 cols), BK=32, 16 MFMA/barrier-pair
__global__ __launch_bounds__(256) void k_gemm1_mfma(const float* __restrict__ x,
                                                    const unsigned short* __restrict__ w1t,
                                                    const float* __restrict__ dinv,
                                                    unsigned short* __restrict__ h1b) {
    __shared__ unsigned short Asub[128 * 32];  // 8 KB
    __shared__ unsigned short Bsub[128 * 32];  // 8 KB
    const int tid  = threadIdx.x;
    const int w    = tid >> 6;
    const int lane = tid & 63;
    const int row0 = blockIdx.x * 128;
    const int r  = lane & 15;
    const int kg = lane >> 4;

    f32x4 acc[2][8] = {};

    for (int k0 = 0; k0 < IN_DIM; k0 += 32) {
        // A stage: 128 rows x 32 k (f32 -> bf16), 512 16B-chunks, 2/thread
#pragma unroll
        for (int i = 0; i < 2; ++i) {
            int q = tid + i * 256;
            int ar = q >> 2, as = q & 3;
            int asw = as ^ (ar & 3);
            uint4 pk = make_uint4(0, 0, 0, 0);
            int grow = row0 + ar;
            if (grow < N_NODES) {
                const float4* p = (const float4*)(x + (size_t)grow * IN_DIM + k0 + as * 8);
                float4 v0 = p[0], v1 = p[1];
                pk.x = f2bf(v0.x) | (f2bf(v0.y) << 16);
                pk.y = f2bf(v0.z) | (f2bf(v0.w) << 16);
                pk.z = f2bf(v1.x) | (f2bf(v1.y) << 16);
                pk.w = f2bf(v1.z) | (f2bf(v1.w) << 16);
            }
            *(uint4*)(Asub + ar * 32 + asw * 8) = pk;
        }
        // B stage: 128 cols x 32 k from w1t
#pragma unroll
        for (int i = 0; i < 2; ++i) {
            int q = tid + i * 256;
            int col = q >> 2, slot = q & 3;
            int sl2 = slot ^ (col & 3);
            *(uint4*)(Bsub + col * 32 + sl2 * 8) =
                *(const uint4*)(w1t + (size_t)col * IN_DIM + k0 + slot * 8);
        }
        __syncthreads();

        bf16x8 af0 = *(const bf16x8*)(Asub + (w * 32 + r) * 32 + ((kg ^ (r & 3)) * 8));
        bf16x8 af1 = *(const bf16x8*)(Asub + (w * 32 + 16 + r) * 32 + ((kg ^ (r & 3)) * 8));
#pragma unroll
        for (int f = 0; f < 8; ++f) {
            bf16x8 bfr = *(const bf16x8*)(Bsub + (f * 16 + r) * 32 + ((kg ^ (r & 3)) * 8));
            acc[0][f] = __builtin_amdgcn_mfma_f32_16x16x32_bf16(af0, bfr, acc[0][f], 0, 0, 0);
            acc[1][f] = __builtin_amdgcn_mfma_f32_16x16x32_bf16(af1, bfr, acc[1][f], 0, 0, 0);
        }
        __syncthreads();
    }

    // D: row = w*32 + a*16 + kg*4 + v, col = f*16 + r
#pragma unroll
    for (int a = 0; a < 2; ++a) {
        float dv[4];
#pragma unroll
        for (int v = 0; v < 4; ++v) {
            int gr = row0 + w * 32 + a * 16 + kg * 4 + v;
            dv[v] = (gr < N_NODES) ? dinv[gr] : 0.f;
        }
#pragma unroll
        for (int f = 0; f < 8; ++f)
#pragma unroll
            for (int v = 0; v < 4; ++v) {
                int gr = row0 + w * 32 + a * 16 + kg * 4 + v;
                if (gr < N_NODES)
                    h1b[(size_t)gr * HID_DIM + f * 16 + r] =
                        (unsigned short)f2bf(acc[a][f][v] * dv[v]);
            }
    }
}

// ---------------- layer-1 gather (pure): h1a = relu(di*sum + b1), bf16 ----------------
__global__ __launch_bounds__(256) void k_layer1(const unsigned short* __restrict__ h1b,
                                                const float* __restrict__ dinv,
                                                const float* __restrict__ b1,
                                                const int* __restrict__ row_beg,
                                                const int* __restrict__ row_end,
                                                const int* __restrict__ csr,
                                                unsigned short* __restrict__ h1a) {
    const int w    = threadIdx.x >> 6;
    const int lane = threadIdx.x & 63;
    const int c0   = lane * 2;
    const float bb0 = b1[c0], bb1 = b1[c0 + 1];

    const int node = blockIdx.x * 4 + w;
    const float di = dinv[node];

    unsigned int us = *(const unsigned int*)(h1b + (size_t)node * HID_DIM + c0);
    f32x2 acc;
    acc.x = bf2f((unsigned short)us);
    acc.y = bf2f((unsigned short)(us >> 16));

    int j = row_beg[node];
    const int je = row_end[node];
    for (; j + 16 <= je; j += 16) {
        int4 i0 = *(const int4*)(csr + j);
        int4 i1 = *(const int4*)(csr + j + 4);
        int4 i2 = *(const int4*)(csr + j + 8);
        int4 i3 = *(const int4*)(csr + j + 12);
        unsigned int uu[16];
        uu[0]  = *(const unsigned int*)(h1b + (size_t)i0.x * HID_DIM + c0);
        uu[1]  = *(const unsigned int*)(h1b + (size_t)i0.y * HID_DIM + c0);
        uu[2]  = *(const unsigned int*)(h1b + (size_t)i0.z * HID_DIM + c0);
        uu[3]  = *(const unsigned int*)(h1b + (size_t)i0.w * HID_DIM + c0);
        uu[4]  = *(const unsigned int*)(h1b + (size_t)i1.x * HID_DIM + c0);
        uu[5]  = *(const unsigned int*)(h1b + (size_t)i1.y * HID_DIM + c0);
        uu[6]  = *(const unsigned int*)(h1b + (size_t)i1.z * HID_DIM + c0);
        uu[7]  = *(const unsigned int*)(h1b + (size_t)i1.w * HID_DIM + c0);
        uu[8]  = *(const unsigned int*)(h1b + (size_t)i2.x * HID_DIM + c0);
        uu[9]  = *(const unsigned int*)(h1b + (size_t)i2.y * HID_DIM + c0);
        uu[10] = *(const unsigned int*)(h1b + (size_t)i2.z * HID_DIM + c0);
        uu[11] = *(const unsigned int*)(h1b + (size_t)i2.w * HID_DIM + c0);
        uu[12] = *(const unsigned int*)(h1b + (size_t)i3.x * HID_DIM + c0);
        uu[13] = *(const unsigned int*)(h1b + (size_t)i3.y * HID_DIM + c0);
        uu[14] = *(const unsigned int*)(h1b + (size_t)i3.z * HID_DIM + c0);
        uu[15] = *(const unsigned int*)(h1b + (size_t)i3.w * HID_DIM + c0);
#pragma unroll
        for (int u = 0; u < 16; ++u) {
            f32x2 t;
            t.x = __uint_as_float(uu[u] << 16);
            t.y = __uint_as_float(uu[u] & 0xffff0000u);
            acc += t;
        }
    }
    if (j < je) {  // exactly one 8-batch remains
        int4 i0 = *(const int4*)(csr + j);
        int4 i1 = *(const int4*)(csr + j + 4);
        unsigned int uu[8];
        uu[0] = *(const unsigned int*)(h1b + (size_t)i0.x * HID_DIM + c0);
        uu[1] = *(const unsigned int*)(h1b + (size_t)i0.y * HID_DIM + c0);
        uu[2] = *(const unsigned int*)(h1b + (size_t)i0.z * HID_DIM + c0);
        uu[3] = *(const unsigned int*)(h1b + (size_t)i0.w * HID_DIM + c0);
        uu[4] = *(const unsigned int*)(h1b + (size_t)i1.x * HID_DIM + c0);
        uu[5] = *(const unsigned int*)(h1b + (size_t)i1.y * HID_DIM + c0);
        uu[6] = *(const unsigned int*)(h1b + (size_t)i1.z * HID_DIM + c0);
        uu[7] = *(const unsigned int*)(h1b + (size_t)i1.w * HID_DIM + c0);
#pragma unroll
        for (int u = 0; u < 8; ++u) {
            f32x2 t;
            t.x = __uint_as_float(uu[u] << 16);
            t.y = __uint_as_float(uu[u] & 0xffff0000u);
            acc += t;
        }
    }

    float r0 = fmaxf(fmaf(di, acc.x, bb0), 0.f);
    float r1 = fmaxf(fmaf(di, acc.y, bb1), 0.f);
    *(unsigned int*)(h1a + (size_t)node * HID_DIM + c0) = f2bf(r0) | (f2bf(r1) << 16);
}

// ---------------- GEMM2 (MFMA): h2b[N][40](bf16) = dinv * (h1a @ W2) ----------------
__global__ __launch_bounds__(256) void k_gemm2_mfma(const unsigned short* __restrict__ h1a,
                                                    const unsigned short* __restrict__ w2t,
                                                    const float* __restrict__ dinv,
                                                    unsigned short* __restrict__ h2b) {
    __shared__ unsigned short Bs[N2 * HID_DIM];  // 12 KB
    const int tid = threadIdx.x;
#pragma unroll
    for (int i = tid; i < N2 * HID_DIM / 8; i += 256) {
        int row = i >> 4, slot = i & 15;
        *(uint4*)(Bs + row * HID_DIM + (slot ^ (row & 7)) * 8) =
            *(const uint4*)(w2t + (size_t)row * HID_DIM + slot * 8);
    }
    __syncthreads();

    const int w    = tid >> 6;
    const int lane = tid & 63;
    const int r  = lane & 15;
    const int kg = lane >> 4;
    const int row0 = blockIdx.x * 64 + w * 16;

    bf16x8 bfr[4][3];
#pragma unroll
    for (int ks = 0; ks < 4; ++ks)
#pragma unroll
        for (int f = 0; f < 3; ++f) {
            int row = f * 16 + r;
            int slot = ks * 4 + kg;
            bfr[ks][f] = *(const bf16x8*)(Bs + row * HID_DIM + (slot ^ (row & 7)) * 8);
        }

    f32x4 acc[3] = {};
#pragma unroll
    for (int ks = 0; ks < 4; ++ks) {
        bf16x8 af = *(const bf16x8*)(h1a + (size_t)(row0 + r) * HID_DIM + ks * 32 + kg * 8);
#pragma unroll
        for (int f = 0; f < 3; ++f)
            acc[f] = __builtin_amdgcn_mfma_f32_16x16x32_bf16(af, bfr[ks][f], acc[f], 0, 0, 0);
    }

    float dv[4];
#pragma unroll
    for (int v = 0; v < 4; ++v) {
        int gr = row0 + kg * 4 + v;
        dv[v] = (gr < N_NODES) ? dinv[gr] : 0.f;
    }
#pragma unroll
    for (int f = 0; f < 3; ++f) {
        int col = f * 16 + r;
        if (col < OUT_DIM) {
#pragma unroll
            for (int v = 0; v < 4; ++v) {
                int gr = row0 + kg * 4 + v;
                if (gr < N_NODES)
                    h2b[(size_t)gr * H2S + col] = (unsigned short)f2bf(acc[f][v] * dv[v]);
            }
        }
    }
}

// ---------------- gather layer 2 (unmasked pure sum) + bias + log_softmax ----------------
__global__ __launch_bounds__(256) void k_gather2(const unsigned short* __restrict__ h2b,
                                                 const float* __restrict__ dinv,
                                                 const float* __restrict__ b2,
                                                 const int* __restrict__ row_beg,
                                                 const int* __restrict__ row_end,
                                                 const int* __restrict__ csr,
                                                 float* __restrict__ out) {
    const int node = blockIdx.x * 4 + (threadIdx.x >> 6);
    const int lane = threadIdx.x & 63;
    const bool act = lane < OUT_DIM;
    const float di = dinv[node];

    float a = bf2f(h2b[(size_t)node * H2S + lane]);  // over-row read for pad lanes; masked below

    int j = row_beg[node];
    const int je = row_end[node];
    for (; j + 16 <= je; j += 16) {
        int4 i0 = *(const int4*)(csr + j);
        int4 i1 = *(const int4*)(csr + j + 4);
        int4 i2 = *(const int4*)(csr + j + 8);
        int4 i3 = *(const int4*)(csr + j + 12);
        unsigned short hv[16];
        hv[0]  = h2b[(size_t)i0.x * H2S + lane];
        hv[1]  = h2b[(size_t)i0.y * H2S + lane];
        hv[2]  = h2b[(size_t)i0.z * H2S + lane];
        hv[3]  = h2b[(size_t)i0.w * H2S + lane];
        hv[4]  = h2b[(size_t)i1.x * H2S + lane];
        hv[5]  = h2b[(size_t)i1.y * H2S + lane];
        hv[6]  = h2b[(size_t)i1.z * H2S + lane];
        hv[7]  = h2b[(size_t)i1.w * H2S + lane];
        hv[8]  = h2b[(size_t)i2.x * H2S + lane];
        hv[9]  = h2b[(size_t)i2.y * H2S + lane];
        hv[10] = h2b[(size_t)i2.z * H2S + lane];
        hv[11] = h2b[(size_t)i2.w * H2S + lane];
        hv[12] = h2b[(size_t)i3.x * H2S + lane];
        hv[13] = h2b[(size_t)i3.y * H2S + lane];
        hv[14] = h2b[(size_t)i3.z * H2S + lane];
        hv[15] = h2b[(size_t)i3.w * H2S + lane];
#pragma unroll
        for (int u = 0; u < 16; ++u) a += bf2f(hv[u]);
    }
    if (j < je) {
        int4 i0 = *(const int4*)(csr + j);
        int4 i1 = *(const int4*)(csr + j + 4);
        unsigned short hv[8];
        hv[0] = h2b[(size_t)i0.x * H2S + lane];
        hv[1] = h2b[(size_t)i0.y * H2S + lane];
        hv[2] = h2b[(size_t)i0.z * H2S + lane];
        hv[3] = h2b[(size_t)i0.w * H2S + lane];
        hv[4] = h2b[(size_t)i1.x * H2S + lane];
        hv[5] = h2b[(size_t)i1.y * H2S + lane];
        hv[6] = h2b[(size_t)i1.z * H2S + lane];
        hv[7] = h2b[(size_t)i1.w * H2S + lane];
#pragma unroll
        for (int u = 0; u < 8; ++u) a += bf2f(hv[u]);
    }

    float v = act ? fmaf(di, a, b2[lane]) : -INFINITY;
    float m = v;
#pragma unroll
    for (int off = 32; off > 0; off >>= 1) m = fmaxf(m, __shfl_xor(m, off));
    float ex = act ? expf(v - m) : 0.f;
    float s = ex;
#pragma unroll
    for (int off = 32; off > 0; off >>= 1) s += __shfl_xor(s, off);
    float ls = logf(s);
    if (act) out[(long long)node * OUT_DIM + lane] = v - m - ls;
}

// ---------------- launch ----------------
extern "C" void kernel_launch(void* const* d_in, const int* in_sizes, int n_in,
                              void* d_out, int out_size, void* d_ws, size_t ws_size,
                              hipStream_t stream) {
    const float* x  = (const float*)d_in[0];
    const int*   ei = (const int*)d_in[1];
    const float* W1 = (const float*)d_in[2];
    const float* b1 = (const float*)d_in[3];
    const float* W2 = (const float*)d_in[4];
    const float* b2 = (const float*)d_in[5];
    float* out = (float*)d_out;

    const int* esrc = ei;
    const int* edst = ei + N_EDGES;

    char* w = (char*)d_ws;
    unsigned int* part = (unsigned int*)w;  w += sizeof(unsigned int) * (size_t)NB * BCAP;  // 8.0 MB
    int*    csr     = (int*)w;    w += sizeof(int) * (size_t)NB * SEGSTRIDE;  // 9.6 MB
    int*    row_beg = (int*)w;    w += sizeof(int) * NROWS;
    int*    row_end = (int*)w;    w += sizeof(int) * NROWS;
    float*  dinv    = (float*)w;  w += sizeof(float) * NROWS;
    int*    gcursor = (int*)w;    w += sizeof(int) * 256;
    unsigned short* h1b = (unsigned short*)w;  w += sizeof(short) * (size_t)NROWS * HID_DIM;
    unsigned short* h1a = (unsigned short*)w;  w += sizeof(short) * (size_t)NROWS * HID_DIM;
    unsigned short* h2b = (unsigned short*)w;  w += sizeof(short) * (size_t)NROWS * H2S;  // 4.0 MB
    unsigned short* w1t = (unsigned short*)w;  w += sizeof(short) * HID_DIM * IN_DIM;
    unsigned short* w2t = (unsigned short*)w;  w += sizeof(short) * N2 * HID_DIM;

    // CSR build (padded segments, fixed stride)
    k_init<<<1, 256, 0, stream>>>(gcursor, h1b, h2b);
    k_part<<<NPB, 256, 0, stream>>>(esrc, edst, gcursor, part);
    k_bucket<<<NB, 256, 0, stream>>>(part, gcursor, row_beg, row_end, dinv, csr);

    // weights prep
    k_w1t<<<HID_DIM, IN_DIM, 0, stream>>>(W1, w1t);
    k_w2t<<<N2, HID_DIM, 0, stream>>>(W2, w2t);

    // layer 1 GEMM via MFMA (pre-scaled by dinv), 128-row tiles
    k_gemm1_mfma<<<NROWS / 128, 256, 0, stream>>>(x, w1t, dinv, h1b);

    // gather1 (+ReLU) -> h1a
    k_layer1<<<N_NODES / 4, 256, 0, stream>>>(h1b, dinv, b1, row_beg, row_end, csr, h1a);

    // GEMM2 via MFMA -> h2b (pre-scaled by dinv)
    k_gemm2_mfma<<<NROWS / 64, 256, 0, stream>>>(h1a, w2t, dinv, h2b);

    // gather2 + log_softmax
    k_gather2<<<N_NODES / 4, 256, 0, stream>>>(h2b, dinv, b2, row_beg, row_end, csr, out);
}